// Round 2
// baseline (6777.068 us; speedup 1.0000x reference)
//
#include <hip/hip_runtime.h>
#include <math.h>

typedef _Float16 f16x8 __attribute__((ext_vector_type(8)));
typedef _Float16 f16x4 __attribute__((ext_vector_type(4)));
typedef float f32x4 __attribute__((ext_vector_type(4)));

constexpr int B_ = 4, N_ = 2048, E_ = 16384;
constexpr int D_ = 10, DM_ = 256, NH_ = 8, FE_ = 9;
constexpr int BN_ = B_ * N_;   // 8192
constexpr int BE_ = B_ * E_;   // 65536

#define DEVI __device__ __forceinline__

DEVI _Float16 f2h(float f) { return (_Float16)f; }

// ---------------- setup kernels ----------------

__global__ void init_state(const int* __restrict__ bus, const float* __restrict__ V0,
                           float* v, float* th, float* m, float* pm, float* qm,
                           int* counts) {
  int t = blockIdx.x * blockDim.x + threadIdx.x;
  if (t >= BN_) return;
  int bt = bus[t];
  pm[t] = (bt == 1) ? 0.f : 1.f;
  qm[t] = (bt == 1 || bt == 2) ? 0.f : 1.f;
  v[t] = V0[2 * t];
  th[t] = V0[2 * t + 1];
  for (int d = 0; d < D_; ++d) m[(size_t)t * D_ + d] = 0.f;
  counts[t] = 0;
}

// T = A / clip(rowsum), A = sqrt(G^2+Bm^2) with zero diagonal; stored fp16
__global__ __launch_bounds__(256) void build_T(const float* __restrict__ G,
    const float* __restrict__ Bm, _Float16* __restrict__ Tb) {
  int row = blockIdx.x;  // 0..8191 (b*N + i)
  int i = row & (N_ - 1);
  const float* Gr = G + (size_t)row * N_;
  const float* Br = Bm + (size_t)row * N_;
  float a[8];
  float s = 0.f;
#pragma unroll
  for (int u = 0; u < 8; ++u) {
    int j = threadIdx.x + u * 256;
    float g = Gr[j], b = Br[j];
    float av = sqrtf(g * g + b * b);
    if (j == i) av = 0.f;
    a[u] = av;
    s += av;
  }
  __shared__ float red[4];
  for (int off = 32; off; off >>= 1) s += __shfl_down(s, off);
  int lane = threadIdx.x & 63, wave = threadIdx.x >> 6;
  if (lane == 0) red[wave] = s;
  __syncthreads();
  float tot = red[0] + red[1] + red[2] + red[3];
  float inv = 1.f / fmaxf(tot, 1e-12f);
#pragma unroll
  for (int u = 0; u < 8; ++u) {
    int j = threadIdx.x + u * 256;
    Tb[(size_t)row * N_ + j] = f2h(a[u] * inv);
  }
}

__global__ void edge_prep(const int* __restrict__ ei, const float* __restrict__ efeat,
    const float* __restrict__ We, const float* __restrict__ be,
    float* __restrict__ eb, int* __restrict__ srcf, int* __restrict__ dstf,
    int* __restrict__ counts) {
  int t = blockIdx.x * blockDim.x + threadIdx.x;
  if (t >= BE_) return;
  int b = t / E_, e = t - b * E_;
  int src = ei[(size_t)b * 2 * E_ + e];
  int dst = ei[(size_t)b * 2 * E_ + E_ + e];
  srcf[t] = src + b * N_;
  int df = dst + b * N_;
  dstf[t] = df;
  atomicAdd(&counts[df], 1);
  float fv[FE_];
#pragma unroll
  for (int f = 0; f < FE_; ++f) fv[f] = efeat[(size_t)t * FE_ + f];
#pragma unroll
  for (int h = 0; h < NH_; ++h) {
    float s = be[h];
#pragma unroll
    for (int f = 0; f < FE_; ++f) s += fv[f] * We[f * NH_ + h];
    eb[(size_t)t * NH_ + h] = s;
  }
}

__global__ void scan_kernel(const int* __restrict__ counts, int* __restrict__ offs,
                            int* __restrict__ cursor) {
  __shared__ int part[256];
  int t = threadIdx.x;
  int base = t * 32;
  int loc[32];
  int s = 0;
#pragma unroll
  for (int i = 0; i < 32; ++i) { loc[i] = counts[base + i]; s += loc[i]; }
  part[t] = s;
  __syncthreads();
  for (int off = 1; off < 256; off <<= 1) {
    int vv = (t >= off) ? part[t - off] : 0;
    __syncthreads();
    part[t] += vv;
    __syncthreads();
  }
  int run = part[t] - s;  // exclusive
#pragma unroll
  for (int i = 0; i < 32; ++i) {
    offs[base + i] = run;
    cursor[base + i] = run;
    run += loc[i];
  }
  if (t == 255) offs[BN_] = run;
}

__global__ void scatter_kernel(const int* __restrict__ dstf, int* cursor,
                               int* __restrict__ perm) {
  int t = blockIdx.x * blockDim.x + threadIdx.x;
  if (t >= BE_) return;
  int d = dstf[t];
  int pos = atomicAdd(&cursor[d], 1);
  perm[pos] = t;
}

__global__ void prep_weights(const float* Wq, const float* bq, const float* Wk,
    const float* bk, const float* Wv, const float* bvv, const float* Wo,
    const float* Wf1, const float* Wf2, const float* Wth, const float* bth,
    const float* Wvh, const float* bvh, const float* Wm, const float* bm,
    _Float16* Wqkvt, float* bqkv, _Float16* Wot,
    _Float16* Wf1t, _Float16* Wf2t, float* Wheads, float* bheads) {
  int i = blockIdx.x * blockDim.x + threadIdx.x;
  if (i < 768 * 256) {
    int n = i >> 8, kk = i & 255;
    float val = n < 256 ? Wq[kk * 256 + n]
              : n < 512 ? Wk[kk * 256 + (n - 256)] : Wv[kk * 256 + (n - 512)];
    Wqkvt[n * 256 + kk] = f2h(val);
    return;
  }
  i -= 768 * 256;
  if (i < 256 * 256) {
    int n = i >> 8, kk = i & 255;
    Wot[n * 256 + kk] = f2h(Wo[kk * 256 + n]);
    return;
  }
  i -= 256 * 256;
  if (i < 1024 * 256) {
    int n = i >> 8, kk = i & 255;  // n 0..1023, kk 0..255
    Wf1t[n * 256 + kk] = f2h(Wf1[kk * 1024 + n]);
    return;
  }
  i -= 1024 * 256;
  if (i < 256 * 1024) {
    int n = i >> 10, kk = i & 1023;  // n 0..255, kk 0..1023
    Wf2t[n * 1024 + kk] = f2h(Wf2[kk * 256 + n]);
    return;
  }
  i -= 256 * 1024;
  if (i < 30 * 3072) {
    int k = i / 3072, j = i - k * 3072;
    int row = j / 12, o = j - row * 12;
    float val = o == 0 ? Wth[k * 256 + row]
              : o == 1 ? Wvh[k * 256 + row] : Wm[k * 2560 + row * 10 + (o - 2)];
    Wheads[k * 3072 + j] = val;
    return;
  }
  i -= 30 * 3072;
  if (i < 360) {
    int k = i / 12, o = i - k * 12;
    bheads[i] = o == 0 ? bth[k] : o == 1 ? bvh[k] : bm[k * 10 + (o - 2)];
    return;
  }
  i -= 360;
  if (i < 768) {
    bqkv[i] = i < 256 ? bq[i] : i < 512 ? bk[i - 256] : bvv[i - 512];
  }
}

// ---------------- per-step kernels ----------------

__global__ void ef_kernel(const float* __restrict__ v, const float* __restrict__ th,
                          float* __restrict__ e, float* __restrict__ f) {
  int t = blockIdx.x * blockDim.x + threadIdx.x;
  if (t >= BN_) return;
  float vv = v[t], tt = th[t];
  e[t] = vv * cosf(tt);
  f[t] = vv * sinf(tt);
}

// Ire = G@e - Bm@f ; Iim = G@f + Bm@e   (fused single pass over G,Bm)
__global__ __launch_bounds__(256) void matvec_kernel(const float* __restrict__ G,
    const float* __restrict__ Bm, const float* __restrict__ e,
    const float* __restrict__ f, float* __restrict__ Ire, float* __restrict__ Iim) {
  int b = blockIdx.y;
  __shared__ float se[N_], sf[N_];
  for (int i = threadIdx.x; i < N_; i += 256) {
    se[i] = e[b * N_ + i];
    sf[i] = f[b * N_ + i];
  }
  __syncthreads();
  int wave = threadIdx.x >> 6, lane = threadIdx.x & 63;
#pragma unroll
  for (int rr = 0; rr < 2; ++rr) {
    int row = blockIdx.x * 8 + wave * 2 + rr;
    const float* Gr = G + ((size_t)b * N_ + row) * N_;
    const float* Br = Bm + ((size_t)b * N_ + row) * N_;
    float sre = 0.f, sim = 0.f;
    for (int j = lane * 4; j < N_; j += 256) {
      float4 g4 = *(const float4*)(Gr + j);
      float4 b4 = *(const float4*)(Br + j);
      float4 e4 = *(const float4*)(&se[j]);
      float4 f4 = *(const float4*)(&sf[j]);
      sre += g4.x * e4.x - b4.x * f4.x + g4.y * e4.y - b4.y * f4.y
           + g4.z * e4.z - b4.z * f4.z + g4.w * e4.w - b4.w * f4.w;
      sim += g4.x * f4.x + b4.x * e4.x + g4.y * f4.y + b4.y * e4.y
           + g4.z * f4.z + b4.z * e4.z + g4.w * f4.w + b4.w * e4.w;
    }
    for (int off = 32; off; off >>= 1) {
      sre += __shfl_down(sre, off);
      sim += __shfl_down(sim, off);
    }
    if (lane == 0) { Ire[b * N_ + row] = sre; Iim[b * N_ + row] = sim; }
  }
}

// ns^T fp16 [B][16][N] (khop operand) + fp32 copy (direct path)
// channels: v,th,DP,DQ,m0..m9,0,0
__global__ void ns_kernel(const float* __restrict__ v, const float* __restrict__ th,
    const float* __restrict__ e, const float* __restrict__ f,
    const float* __restrict__ Ire, const float* __restrict__ Iim,
    const float* __restrict__ P, const float* __restrict__ Q,
    const float* __restrict__ pm, const float* __restrict__ qm,
    const float* __restrict__ m, _Float16* __restrict__ nsT,
    float* __restrict__ nsF) {
  int t = blockIdx.x * blockDim.x + threadIdx.x;
  if (t >= BN_) return;
  int b = t >> 11, n = t & (N_ - 1);
  float ev = e[t], fv = f[t], ir = Ire[t], ii = Iim[t];
  float DP = (P[t] - (ev * ir + fv * ii)) * pm[t];
  float DQ = (Q[t] - (fv * ir - ev * ii)) * qm[t];
  size_t base = (size_t)b * 16 * N_ + n;
  float ch[14];
  ch[0] = v[t]; ch[1] = th[t]; ch[2] = DP; ch[3] = DQ;
#pragma unroll
  for (int d = 0; d < 10; ++d) ch[4 + d] = m[(size_t)t * 10 + d];
#pragma unroll
  for (int c = 0; c < 14; ++c) {
    nsT[base + (size_t)c * N_] = f2h(ch[c]);
    nsF[base + (size_t)c * N_] = ch[c];
  }
  nsT[base + 14 * (size_t)N_] = (_Float16)0.f;
  nsT[base + 15 * (size_t)N_] = (_Float16)0.f;
}

// Hout^T = (T @ Hin)^T via MFMA; acc^T += w * Hout^T  (w pre-divided by Z)
__global__ __launch_bounds__(256) void khop_kernel(const _Float16* __restrict__ Tb,
    const _Float16* __restrict__ HinT, _Float16* __restrict__ HoutT,
    float* __restrict__ accT, float w, int first) {
  int b = blockIdx.y;
  int m0 = blockIdx.x * 16;
  int wave = threadIdx.x >> 6, lane = threadIdx.x & 63;
  int lm = lane & 15, lq = lane >> 4;
  __shared__ float red[4][16][17];
  f32x4 acc = {0.f, 0.f, 0.f, 0.f};
  const _Float16* Trow = Tb + ((size_t)b * N_ + m0 + lm) * N_ + wave * 512 + lq * 8;
  const _Float16* Hrow = HinT + ((size_t)b * 16 + lm) * N_ + wave * 512 + lq * 8;
#pragma unroll 4
  for (int k = 0; k < 512; k += 32) {
    f16x8 a = *(const f16x8*)(Trow + k);
    f16x8 hb = *(const f16x8*)(Hrow + k);
    acc = __builtin_amdgcn_mfma_f32_16x16x32_f16(a, hb, acc, 0, 0, 0);
  }
#pragma unroll
  for (int r = 0; r < 4; ++r) red[wave][lq * 4 + r][lm] = acc[r];
  __syncthreads();
  int c = threadIdx.x >> 4, r = threadIdx.x & 15;
  float s = red[0][r][c] + red[1][r][c] + red[2][r][c] + red[3][r][c];
  size_t o = ((size_t)b * 16 + c) * N_ + m0 + r;
  if (HoutT) HoutT[o] = f2h(s);
  if (first) accT[o] = w * s; else accT[o] += w * s;
}

// x0 = [ns, khop] @ Win + b_in  (K=28, fp32), also writes fp16 copy
__global__ __launch_bounds__(256) void input_gemm(const float* __restrict__ nsF,
    const float* __restrict__ accT, const float* __restrict__ Win,
    const float* __restrict__ bin, float* __restrict__ x0,
    _Float16* __restrict__ xh) {
  int node = blockIdx.x;
  int b = node >> 11, n = node & (N_ - 1);
  __shared__ float in28[28];
  int t = threadIdx.x;
  if (t < 14) in28[t] = nsF[((size_t)b * 16 + t) * N_ + n];
  else if (t < 28) in28[t] = accT[((size_t)b * 16 + (t - 14)) * N_ + n];
  __syncthreads();
  float acc = bin[t];
#pragma unroll
  for (int k = 0; k < 28; ++k) acc = fmaf(in28[k], Win[k * DM_ + t], acc);
  x0[(size_t)node * DM_ + t] = acc;
  xh[(size_t)node * DM_ + t] = f2h(acc);
}

// C(M,N) = A(M,K,f16) @ Wt(N,K,f16)^T + bias; optional relu; fp32 and/or f16 out
__global__ __launch_bounds__(256) void gemm_kernel(const _Float16* __restrict__ A,
    const _Float16* __restrict__ Wt, const float* __restrict__ bias,
    float* __restrict__ Cf, _Float16* __restrict__ Ch,
    int N, int K, int relu) {
  int wave = threadIdx.x >> 6, lane = threadIdx.x & 63;
  int wy = wave >> 1, wx = wave & 1;
  int m0 = blockIdx.x * 64 + wy * 32;
  int n0 = blockIdx.y * 64 + wx * 32;
  int lm = lane & 15, lq = lane >> 4;
  f32x4 acc[2][2] = {};
  const _Float16* A0 = A + (size_t)(m0 + lm) * K + lq * 8;
  const _Float16* A1 = A0 + (size_t)16 * K;
  const _Float16* B0 = Wt + (size_t)(n0 + lm) * K + lq * 8;
  const _Float16* B1 = B0 + (size_t)16 * K;
  for (int k = 0; k < K; k += 32) {
    f16x8 a0 = *(const f16x8*)(A0 + k);
    f16x8 a1 = *(const f16x8*)(A1 + k);
    f16x8 b0 = *(const f16x8*)(B0 + k);
    f16x8 b1 = *(const f16x8*)(B1 + k);
    acc[0][0] = __builtin_amdgcn_mfma_f32_16x16x32_f16(a0, b0, acc[0][0], 0, 0, 0);
    acc[0][1] = __builtin_amdgcn_mfma_f32_16x16x32_f16(a0, b1, acc[0][1], 0, 0, 0);
    acc[1][0] = __builtin_amdgcn_mfma_f32_16x16x32_f16(a1, b0, acc[1][0], 0, 0, 0);
    acc[1][1] = __builtin_amdgcn_mfma_f32_16x16x32_f16(a1, b1, acc[1][1], 0, 0, 0);
  }
#pragma unroll
  for (int tm = 0; tm < 2; ++tm)
#pragma unroll
    for (int tn = 0; tn < 2; ++tn) {
      int col = n0 + tn * 16 + lm;
      float bvv = bias ? bias[col] : 0.f;
#pragma unroll
      for (int r = 0; r < 4; ++r) {
        int row = m0 + tm * 16 + lq * 4 + r;
        float val = acc[tm][tn][r] + bvv;
        if (relu) val = fmaxf(val, 0.f);
        size_t o = (size_t)row * N + col;
        if (Cf) Cf[o] = val;
        if (Ch) Ch[o] = f2h(val);
      }
    }
}

// one wave per node: online segment softmax over incoming edges, agg -> fp16
__global__ __launch_bounds__(256) void attn_kernel(const float* __restrict__ qkv,
    const int* __restrict__ offs, const int* __restrict__ perm,
    const int* __restrict__ srcf, const float* __restrict__ eb,
    _Float16* __restrict__ aggh) {
  int node = blockIdx.x * 4 + (threadIdx.x >> 6);
  int lane = threadIdx.x & 63;
  int h = lane >> 3;
  const float4 q4 = *(const float4*)(qkv + (size_t)node * 768 + lane * 4);
  int beg = offs[node], end = offs[node + 1];
  float mx = -3.0e38f, den = 0.f;
  float4 acc = {0.f, 0.f, 0.f, 0.f};
  for (int j = beg; j < end; ++j) {
    int e = perm[j];
    int s = srcf[e];
    const float* base = qkv + (size_t)s * 768 + lane * 4;
    float4 k4 = *(const float4*)(base + 256);
    float4 v4 = *(const float4*)(base + 512);
    float p = q4.x * k4.x + q4.y * k4.y + q4.z * k4.z + q4.w * k4.w;
    p += __shfl_xor(p, 1);
    p += __shfl_xor(p, 2);
    p += __shfl_xor(p, 4);
    float score = p * 0.17677669529663687f + eb[(size_t)e * 8 + h];
    float nm = fmaxf(mx, score);
    float sc = __expf(mx - nm);
    float w = __expf(score - nm);
    den = den * sc + w;
    acc.x = acc.x * sc + w * v4.x;
    acc.y = acc.y * sc + w * v4.y;
    acc.z = acc.z * sc + w * v4.z;
    acc.w = acc.w * sc + w * v4.w;
    mx = nm;
  }
  float inv = den > 0.f ? 1.f / den : 0.f;
  f16x4 o;
  o[0] = f2h(acc.x * inv);
  o[1] = f2h(acc.y * inv);
  o[2] = f2h(acc.z * inv);
  o[3] = f2h(acc.w * inv);
  *(f16x4*)(aggh + (size_t)node * DM_ + lane * 4) = o;
}

// y = LN(x + add); wave per node
__global__ __launch_bounds__(256) void ln_kernel(const float* __restrict__ x,
    const float* __restrict__ add, const float* __restrict__ g,
    const float* __restrict__ bb, float* __restrict__ yf,
    _Float16* __restrict__ yh) {
  int node = blockIdx.x * 4 + (threadIdx.x >> 6);
  int lane = threadIdx.x & 63;
  size_t base = (size_t)node * DM_ + lane * 4;
  float4 s4 = *(const float4*)(x + base);
  float4 a4 = *(const float4*)(add + base);
  s4.x += a4.x; s4.y += a4.y; s4.z += a4.z; s4.w += a4.w;
  float sum = s4.x + s4.y + s4.z + s4.w;
  float sq = s4.x * s4.x + s4.y * s4.y + s4.z * s4.z + s4.w * s4.w;
  for (int off = 32; off; off >>= 1) {
    sum += __shfl_down(sum, off);
    sq += __shfl_down(sq, off);
  }
  sum = __shfl(sum, 0);
  sq = __shfl(sq, 0);
  float mu = sum * (1.f / 256.f);
  float var = sq * (1.f / 256.f) - mu * mu;
  float rs = rsqrtf(var + 1e-5f);
  const float4 g4 = *(const float4*)(g + lane * 4);
  const float4 b4 = *(const float4*)(bb + lane * 4);
  float4 y;
  y.x = g4.x * (s4.x - mu) * rs + b4.x;
  y.y = g4.y * (s4.y - mu) * rs + b4.y;
  y.z = g4.z * (s4.z - mu) * rs + b4.z;
  y.w = g4.w * (s4.w - mu) * rs + b4.w;
  *(float4*)(yf + base) = y;
  if (yh) {
    f16x4 o;
    o[0] = f2h(y.x); o[1] = f2h(y.y); o[2] = f2h(y.z); o[3] = f2h(y.w);
    *(f16x4*)(yh + base) = o;
  }
}

// 12 head dots per node (dth, dv, m0..m9); update state
__global__ __launch_bounds__(256) void heads_kernel(const float* __restrict__ x,
    const float* __restrict__ Wh, const float* __restrict__ bh,
    const float* __restrict__ pm, const float* __restrict__ qm,
    float* __restrict__ v, float* __restrict__ th, float* __restrict__ m) {
  int node = blockIdx.x * 4 + (threadIdx.x >> 6);
  int lane = threadIdx.x & 63;
  const float4 xv = *(const float4*)(x + (size_t)node * DM_ + lane * 4);
  int i0 = lane * 4;
  float r[12];
#pragma unroll
  for (int o = 0; o < 12; ++o) {
    float p = xv.x * Wh[(i0 + 0) * 12 + o] + xv.y * Wh[(i0 + 1) * 12 + o]
            + xv.z * Wh[(i0 + 2) * 12 + o] + xv.w * Wh[(i0 + 3) * 12 + o];
    for (int off = 32; off; off >>= 1) p += __shfl_down(p, off);
    r[o] = p;
  }
  if (lane == 0) {
    th[node] += (r[0] + bh[0]) * pm[node];
    v[node] += (r[1] + bh[1]) * qm[node];
#pragma unroll
    for (int d = 0; d < 10; ++d) m[(size_t)node * 10 + d] = r[2 + d] + bh[2 + d];
  }
}

__global__ void out_kernel(const float* __restrict__ v, const float* __restrict__ th,
                           float* __restrict__ out) {
  int t = blockIdx.x * blockDim.x + threadIdx.x;
  if (t >= BN_) return;
  out[2 * t] = v[t];
  out[2 * t + 1] = th[t];
}

// ---------------- launcher ----------------

extern "C" void kernel_launch(void* const* d_in, const int* in_sizes, int n_in,
                              void* d_out, int out_size, void* d_ws, size_t ws_size,
                              hipStream_t stream) {
  const int* bus = (const int*)d_in[0];
  const int* ei = (const int*)d_in[1];
  const float* G = (const float*)d_in[2];
  const float* Bm = (const float*)d_in[3];
  const float* P = (const float*)d_in[4];
  const float* Q = (const float*)d_in[5];
  const float* V0 = (const float*)d_in[6];
  const float* efeat = (const float*)d_in[7];
  const float* Win = (const float*)d_in[8];
  const float* bin = (const float*)d_in[9];
  const float* Wq = (const float*)d_in[10];
  const float* bq = (const float*)d_in[11];
  const float* Wk = (const float*)d_in[12];
  const float* bk = (const float*)d_in[13];
  const float* Wv = (const float*)d_in[14];
  const float* bv = (const float*)d_in[15];
  const float* Wo = (const float*)d_in[16];
  const float* bo = (const float*)d_in[17];
  const float* We = (const float*)d_in[18];
  const float* be = (const float*)d_in[19];
  const float* g1 = (const float*)d_in[20];
  const float* b1 = (const float*)d_in[21];
  const float* g2 = (const float*)d_in[22];
  const float* b2 = (const float*)d_in[23];
  const float* Wf1 = (const float*)d_in[24];
  const float* bf1 = (const float*)d_in[25];
  const float* Wf2 = (const float*)d_in[26];
  const float* bf2 = (const float*)d_in[27];
  const float* Wth = (const float*)d_in[28];
  const float* bth = (const float*)d_in[29];
  const float* Wvh = (const float*)d_in[30];
  const float* bvh = (const float*)d_in[31];
  const float* Wm = (const float*)d_in[32];
  const float* bm = (const float*)d_in[33];
  float* out = (float*)d_out;

  char* p = (char*)d_ws;
  auto alloc = [&](size_t bytes) -> void* {
    void* r = (void*)p;
    p += (bytes + 255) & ~(size_t)255;
    return r;
  };
  _Float16* Tb = (_Float16*)alloc((size_t)BN_ * N_ * 2);      // 33.5 MB
  _Float16* nsT = (_Float16*)alloc((size_t)B_ * 16 * N_ * 2);
  float* nsF = (float*)alloc((size_t)B_ * 16 * N_ * 4);
  _Float16* HTa = (_Float16*)alloc((size_t)B_ * 16 * N_ * 2);
  _Float16* HTb = (_Float16*)alloc((size_t)B_ * 16 * N_ * 2);
  float* accT = (float*)alloc((size_t)B_ * 16 * N_ * 4);
  float* qkv = (float*)alloc((size_t)BN_ * 768 * 4);          // 25.2 MB
  float* x0 = (float*)alloc((size_t)BN_ * 256 * 4);
  float* x1 = (float*)alloc((size_t)BN_ * 256 * 4);
  float* tmp = (float*)alloc((size_t)BN_ * 256 * 4);
  _Float16* xh = (_Float16*)alloc((size_t)BN_ * 256 * 2);
  _Float16* hbuf = (_Float16*)alloc((size_t)BN_ * 1024 * 2);  // 16.8 MB
  float* eb = (float*)alloc((size_t)BE_ * 8 * 4);
  int* srcf = (int*)alloc((size_t)BE_ * 4);
  int* dstf = (int*)alloc((size_t)BE_ * 4);
  int* counts = (int*)alloc((size_t)BN_ * 4);
  int* offs = (int*)alloc((size_t)(BN_ + 1) * 4);
  int* cursor = (int*)alloc((size_t)BN_ * 4);
  int* perm = (int*)alloc((size_t)BE_ * 4);
  _Float16* Wqkvt = (_Float16*)alloc(768 * 256 * 2);
  _Float16* Wot = (_Float16*)alloc(256 * 256 * 2);
  _Float16* Wf1t = (_Float16*)alloc(1024 * 256 * 2);
  _Float16* Wf2t = (_Float16*)alloc(256 * 1024 * 2);
  float* Wheads = (float*)alloc(30 * 3072 * 4);
  float* bheads = (float*)alloc(30 * 12 * 4);
  float* bqkv = (float*)alloc(768 * 4);
  float* v = (float*)alloc((size_t)BN_ * 4);
  float* th = (float*)alloc((size_t)BN_ * 4);
  float* e = (float*)alloc((size_t)BN_ * 4);
  float* f = (float*)alloc((size_t)BN_ * 4);
  float* Ire = (float*)alloc((size_t)BN_ * 4);
  float* Iim = (float*)alloc((size_t)BN_ * 4);
  float* pm = (float*)alloc((size_t)BN_ * 4);
  float* qm = (float*)alloc((size_t)BN_ * 4);
  float* m = (float*)alloc((size_t)BN_ * 10 * 4);

  // hop weights, pre-divided by Z
  double hwd[3], z = 0.0;
  for (int i = 0; i < 3; ++i) {
    hwd[i] = exp(-((double)(i + 1) * (i + 1)) / (2.0 * 1.5 * 1.5));
    z += hwd[i];
  }
  float hw0 = (float)(hwd[0] / z), hw1 = (float)(hwd[1] / z), hw2 = (float)(hwd[2] / z);

  init_state<<<32, 256, 0, stream>>>(bus, V0, v, th, m, pm, qm, counts);
  build_T<<<8192, 256, 0, stream>>>(G, Bm, Tb);
  edge_prep<<<BE_ / 256, 256, 0, stream>>>(ei, efeat, We, be, eb, srcf, dstf, counts);
  scan_kernel<<<1, 256, 0, stream>>>(counts, offs, cursor);
  scatter_kernel<<<BE_ / 256, 256, 0, stream>>>(dstf, cursor, perm);
  prep_weights<<<(879720 + 255) / 256, 256, 0, stream>>>(
      Wq, bq, Wk, bk, Wv, bv, Wo, Wf1, Wf2, Wth, bth, Wvh, bvh, Wm, bm,
      Wqkvt, bqkv, Wot, Wf1t, Wf2t, Wheads, bheads);

  for (int k = 0; k < 30; ++k) {
    ef_kernel<<<32, 256, 0, stream>>>(v, th, e, f);
    matvec_kernel<<<dim3(256, 4), 256, 0, stream>>>(G, Bm, e, f, Ire, Iim);
    ns_kernel<<<32, 256, 0, stream>>>(v, th, e, f, Ire, Iim, P, Q, pm, qm, m,
                                      nsT, nsF);
    khop_kernel<<<dim3(128, 4), 256, 0, stream>>>(Tb, nsT, HTa, accT, hw0, 1);
    khop_kernel<<<dim3(128, 4), 256, 0, stream>>>(Tb, HTa, HTb, accT, hw1, 0);
    khop_kernel<<<dim3(128, 4), 256, 0, stream>>>(Tb, HTb, (_Float16*)nullptr,
                                                  accT, hw2, 0);
    input_gemm<<<8192, 256, 0, stream>>>(nsF, accT, Win, bin, x0, xh);
    gemm_kernel<<<dim3(128, 12), 256, 0, stream>>>(xh, Wqkvt, bqkv, qkv, nullptr,
                                                   768, 256, 0);
    attn_kernel<<<2048, 256, 0, stream>>>(qkv, offs, perm, srcf, eb, xh);
    gemm_kernel<<<dim3(128, 4), 256, 0, stream>>>(xh, Wot, bo, tmp, nullptr,
                                                  256, 256, 0);
    ln_kernel<<<2048, 256, 0, stream>>>(x0, tmp, g1, b1, x1, xh);
    gemm_kernel<<<dim3(128, 16), 256, 0, stream>>>(xh, Wf1t, bf1, nullptr, hbuf,
                                                   1024, 256, 1);
    gemm_kernel<<<dim3(128, 4), 256, 0, stream>>>(hbuf, Wf2t, bf2, tmp, nullptr,
                                                  256, 1024, 0);
    ln_kernel<<<2048, 256, 0, stream>>>(x1, tmp, g2, b2, x0, nullptr);
    heads_kernel<<<2048, 256, 0, stream>>>(x0, Wheads + k * 3072, bheads + k * 12,
                                           pm, qm, v, th, m);
  }
  out_kernel<<<32, 256, 0, stream>>>(v, th, out);
}

// Round 3
// 5433.031 us; speedup vs baseline: 1.2474x; 1.2474x over previous
//
#include <hip/hip_runtime.h>
#include <math.h>

typedef _Float16 f16x8 __attribute__((ext_vector_type(8)));
typedef _Float16 f16x4 __attribute__((ext_vector_type(4)));
typedef float f32x4 __attribute__((ext_vector_type(4)));

constexpr int B_ = 4, N_ = 2048, E_ = 16384;
constexpr int D_ = 10, DM_ = 256, NH_ = 8, FE_ = 9;
constexpr int BN_ = B_ * N_;   // 8192
constexpr int BE_ = B_ * E_;   // 65536

#define DEVI __device__ __forceinline__

DEVI _Float16 f2h(float f) { return (_Float16)f; }

// ---------------- setup kernels ----------------

__global__ void init_state(const int* __restrict__ bus, const float* __restrict__ V0,
                           float* v, float* th, float* m, float* pm, float* qm,
                           int* counts) {
  int t = blockIdx.x * blockDim.x + threadIdx.x;
  if (t >= BN_) return;
  int bt = bus[t];
  pm[t] = (bt == 1) ? 0.f : 1.f;
  qm[t] = (bt == 1 || bt == 2) ? 0.f : 1.f;
  v[t] = V0[2 * t];
  th[t] = V0[2 * t + 1];
  for (int d = 0; d < D_; ++d) m[(size_t)t * D_ + d] = 0.f;
  counts[t] = 0;
}

__global__ void cast_GB(const float* __restrict__ G, const float* __restrict__ Bm,
                        _Float16* __restrict__ Gh, _Float16* __restrict__ Bh) {
  size_t t = ((size_t)blockIdx.x * 256 + threadIdx.x) * 4;
  float4 g = *(const float4*)(G + t);
  float4 b = *(const float4*)(Bm + t);
  f16x4 gh, bh;
  gh[0] = f2h(g.x); gh[1] = f2h(g.y); gh[2] = f2h(g.z); gh[3] = f2h(g.w);
  bh[0] = f2h(b.x); bh[1] = f2h(b.y); bh[2] = f2h(b.z); bh[3] = f2h(b.w);
  *(f16x4*)(Gh + t) = gh;
  *(f16x4*)(Bh + t) = bh;
}

// T = A / clip(rowsum), A = sqrt(G^2+Bm^2) with zero diagonal; stored fp16
__global__ __launch_bounds__(256) void build_T(const float* __restrict__ G,
    const float* __restrict__ Bm, _Float16* __restrict__ Tb) {
  int row = blockIdx.x;
  int i = row & (N_ - 1);
  const float* Gr = G + (size_t)row * N_;
  const float* Br = Bm + (size_t)row * N_;
  float a[8];
  float s = 0.f;
#pragma unroll
  for (int u = 0; u < 8; ++u) {
    int j = threadIdx.x + u * 256;
    float g = Gr[j], b = Br[j];
    float av = sqrtf(g * g + b * b);
    if (j == i) av = 0.f;
    a[u] = av;
    s += av;
  }
  __shared__ float red[4];
  for (int off = 32; off; off >>= 1) s += __shfl_down(s, off);
  int lane = threadIdx.x & 63, wave = threadIdx.x >> 6;
  if (lane == 0) red[wave] = s;
  __syncthreads();
  float tot = red[0] + red[1] + red[2] + red[3];
  float inv = 1.f / fmaxf(tot, 1e-12f);
#pragma unroll
  for (int u = 0; u < 8; ++u) {
    int j = threadIdx.x + u * 256;
    Tb[(size_t)row * N_ + j] = f2h(a[u] * inv);
  }
}

__global__ void edge_prep(const int* __restrict__ ei, const float* __restrict__ efeat,
    const float* __restrict__ We, const float* __restrict__ be,
    float* __restrict__ eb, int* __restrict__ srcf, int* __restrict__ dstf,
    int* __restrict__ counts) {
  int t = blockIdx.x * blockDim.x + threadIdx.x;
  if (t >= BE_) return;
  int b = t / E_, e = t - b * E_;
  int src = ei[(size_t)b * 2 * E_ + e];
  int dst = ei[(size_t)b * 2 * E_ + E_ + e];
  srcf[t] = src + b * N_;
  int df = dst + b * N_;
  dstf[t] = df;
  atomicAdd(&counts[df], 1);
  float fv[FE_];
#pragma unroll
  for (int f = 0; f < FE_; ++f) fv[f] = efeat[(size_t)t * FE_ + f];
#pragma unroll
  for (int h = 0; h < NH_; ++h) {
    float s = be[h];
#pragma unroll
    for (int f = 0; f < FE_; ++f) s += fv[f] * We[f * NH_ + h];
    eb[(size_t)t * NH_ + h] = s;
  }
}

__global__ void scan_kernel(const int* __restrict__ counts, int* __restrict__ offs,
                            int* __restrict__ cursor) {
  __shared__ int part[256];
  int t = threadIdx.x;
  int base = t * 32;
  int loc[32];
  int s = 0;
#pragma unroll
  for (int i = 0; i < 32; ++i) { loc[i] = counts[base + i]; s += loc[i]; }
  part[t] = s;
  __syncthreads();
  for (int off = 1; off < 256; off <<= 1) {
    int vv = (t >= off) ? part[t - off] : 0;
    __syncthreads();
    part[t] += vv;
    __syncthreads();
  }
  int run = part[t] - s;
#pragma unroll
  for (int i = 0; i < 32; ++i) {
    offs[base + i] = run;
    cursor[base + i] = run;
    run += loc[i];
  }
  if (t == 255) offs[BN_] = run;
}

__global__ void scatter_kernel(const int* __restrict__ dstf, int* cursor,
                               int* __restrict__ perm) {
  int t = blockIdx.x * blockDim.x + threadIdx.x;
  if (t >= BE_) return;
  int d = dstf[t];
  int pos = atomicAdd(&cursor[d], 1);
  perm[pos] = t;
}

__global__ void prep_weights(const float* Wq, const float* bq, const float* Wk,
    const float* bk, const float* Wv, const float* bvv, const float* Wo,
    const float* Wf1, const float* Wf2, const float* Wth, const float* bth,
    const float* Wvh, const float* bvh, const float* Wm, const float* bm,
    const float* Win,
    _Float16* Wqkvt, float* bqkv, _Float16* Wot,
    _Float16* Wf1t, _Float16* Wf2t, float* Wheads, float* bheads,
    _Float16* Wint) {
  int i = blockIdx.x * blockDim.x + threadIdx.x;
  if (i < 768 * 256) {
    int n = i >> 8, kk = i & 255;
    float val = n < 256 ? Wq[kk * 256 + n]
              : n < 512 ? Wk[kk * 256 + (n - 256)] : Wv[kk * 256 + (n - 512)];
    Wqkvt[n * 256 + kk] = f2h(val);
    return;
  }
  i -= 768 * 256;
  if (i < 256 * 256) {
    int n = i >> 8, kk = i & 255;
    Wot[n * 256 + kk] = f2h(Wo[kk * 256 + n]);
    return;
  }
  i -= 256 * 256;
  if (i < 1024 * 256) {
    int n = i >> 8, kk = i & 255;
    Wf1t[n * 256 + kk] = f2h(Wf1[kk * 1024 + n]);
    return;
  }
  i -= 1024 * 256;
  if (i < 256 * 1024) {
    int n = i >> 10, kk = i & 1023;
    Wf2t[n * 1024 + kk] = f2h(Wf2[kk * 256 + n]);
    return;
  }
  i -= 256 * 1024;
  if (i < 30 * 3072) {
    int k = i / 3072, j = i - k * 3072;
    int row = j / 12, o = j - row * 12;
    float val = o == 0 ? Wth[k * 256 + row]
              : o == 1 ? Wvh[k * 256 + row] : Wm[k * 2560 + row * 10 + (o - 2)];
    Wheads[k * 3072 + j] = val;
    return;
  }
  i -= 30 * 3072;
  if (i < 360) {
    int k = i / 12, o = i - k * 12;
    bheads[i] = o == 0 ? bth[k] : o == 1 ? bvh[k] : bm[k * 10 + (o - 2)];
    return;
  }
  i -= 360;
  if (i < 768) {
    bqkv[i] = i < 256 ? bq[i] : i < 512 ? bk[i - 256] : bvv[i - 512];
    return;
  }
  i -= 768;
  if (i < 256 * 32) {
    int n = i >> 5, kk = i & 31;
    Wint[n * 32 + kk] = (kk < 28) ? f2h(Win[kk * 256 + n]) : (_Float16)0.f;
  }
}

// ---------------- per-step kernels ----------------

// shared epilogue: after full-wave reduce of sre/sim, lanes 0..15 write ns channels
DEVI void ns_epilogue(int b, int row, float sre, float sim, int lane,
                      const float* se, const float* sf,
                      const float* v, const float* th, const float* P,
                      const float* Q, const float* pm, const float* qm,
                      const float* m, _Float16* nsT) {
  for (int off = 1; off < 64; off <<= 1) {
    sre += __shfl_xor(sre, off);
    sim += __shfl_xor(sim, off);
  }
  if (lane < 16) {
    int node = b * N_ + row;
    float val;
    if (lane == 0) val = v[node];
    else if (lane == 1) val = th[node];
    else if (lane == 2) {
      float ee = se[row], ff = sf[row];
      val = (P[node] - (ee * sre + ff * sim)) * pm[node];
    } else if (lane == 3) {
      float ee = se[row], ff = sf[row];
      val = (Q[node] - (ff * sre - ee * sim)) * qm[node];
    } else if (lane < 14) val = m[(size_t)node * 10 + (lane - 4)];
    else val = 0.f;
    nsT[(size_t)b * 16 * N_ + (size_t)lane * N_ + row] = f2h(val);
  }
}

// fused: e,f = v*cos/sin(th) in LDS; Ire/Iim matvec (fp16 G,B); DP/DQ; write nsT
__global__ __launch_bounds__(256) void matvec_ns_f16(const _Float16* __restrict__ Gh,
    const _Float16* __restrict__ Bh, const float* __restrict__ v,
    const float* __restrict__ th, const float* __restrict__ P,
    const float* __restrict__ Q, const float* __restrict__ pm,
    const float* __restrict__ qm, const float* __restrict__ m,
    _Float16* __restrict__ nsT) {
  int b = blockIdx.y;
  __shared__ float se[N_], sf[N_];
  for (int i = threadIdx.x; i < N_; i += 256) {
    float vv = v[b * N_ + i], tt = th[b * N_ + i];
    float sn, cs;
    __sincosf(tt, &sn, &cs);
    se[i] = vv * cs;
    sf[i] = vv * sn;
  }
  __syncthreads();
  int wave = threadIdx.x >> 6, lane = threadIdx.x & 63;
  for (int rr = 0; rr < 4; ++rr) {
    int row = blockIdx.x * 16 + wave * 4 + rr;
    const _Float16* Gr = Gh + ((size_t)b * N_ + row) * N_;
    const _Float16* Br = Bh + ((size_t)b * N_ + row) * N_;
    float sre = 0.f, sim = 0.f;
#pragma unroll
    for (int jj = 0; jj < 4; ++jj) {
      int j = lane * 8 + jj * 512;
      f16x8 g8 = *(const f16x8*)(Gr + j);
      f16x8 b8 = *(const f16x8*)(Br + j);
#pragma unroll
      for (int u = 0; u < 8; ++u) {
        float g = (float)g8[u], bb = (float)b8[u];
        float ee = se[j + u], ff = sf[j + u];
        sre += g * ee - bb * ff;
        sim += g * ff + bb * ee;
      }
    }
    ns_epilogue(b, row, sre, sim, lane, se, sf, v, th, P, Q, pm, qm, m, nsT);
  }
}

// fp32 fallback (if workspace too small for Gh/Bh)
__global__ __launch_bounds__(256) void matvec_ns_f32(const float* __restrict__ G,
    const float* __restrict__ Bm, const float* __restrict__ v,
    const float* __restrict__ th, const float* __restrict__ P,
    const float* __restrict__ Q, const float* __restrict__ pm,
    const float* __restrict__ qm, const float* __restrict__ m,
    _Float16* __restrict__ nsT) {
  int b = blockIdx.y;
  __shared__ float se[N_], sf[N_];
  for (int i = threadIdx.x; i < N_; i += 256) {
    float vv = v[b * N_ + i], tt = th[b * N_ + i];
    float sn, cs;
    __sincosf(tt, &sn, &cs);
    se[i] = vv * cs;
    sf[i] = vv * sn;
  }
  __syncthreads();
  int wave = threadIdx.x >> 6, lane = threadIdx.x & 63;
  for (int rr = 0; rr < 4; ++rr) {
    int row = blockIdx.x * 16 + wave * 4 + rr;
    const float* Gr = G + ((size_t)b * N_ + row) * N_;
    const float* Br = Bm + ((size_t)b * N_ + row) * N_;
    float sre = 0.f, sim = 0.f;
#pragma unroll
    for (int jj = 0; jj < 8; ++jj) {
      int j = lane * 4 + jj * 256;
      float4 g4 = *(const float4*)(Gr + j);
      float4 b4 = *(const float4*)(Br + j);
      float4 e4 = *(const float4*)(&se[j]);
      float4 f4 = *(const float4*)(&sf[j]);
      sre += g4.x * e4.x - b4.x * f4.x + g4.y * e4.y - b4.y * f4.y
           + g4.z * e4.z - b4.z * f4.z + g4.w * e4.w - b4.w * f4.w;
      sim += g4.x * f4.x + b4.x * e4.x + g4.y * f4.y + b4.y * e4.y
           + g4.z * f4.z + b4.z * e4.z + g4.w * f4.w + b4.w * e4.w;
    }
    ns_epilogue(b, row, sre, sim, lane, se, sf, v, th, P, Q, pm, qm, m, nsT);
  }
}

// Hout^T = (T @ Hin)^T via MFMA; acc^T (+)= w * Hout^T
__global__ __launch_bounds__(256) void khop_kernel(const _Float16* __restrict__ Tb,
    const _Float16* __restrict__ HinT, _Float16* __restrict__ HoutT,
    float* __restrict__ accT, float w, int first) {
  int b = blockIdx.y;
  int m0 = blockIdx.x * 16;
  int wave = threadIdx.x >> 6, lane = threadIdx.x & 63;
  int lm = lane & 15, lq = lane >> 4;
  __shared__ float red[4][16][17];
  f32x4 acc = {0.f, 0.f, 0.f, 0.f};
  const _Float16* Trow = Tb + ((size_t)b * N_ + m0 + lm) * N_ + wave * 512 + lq * 8;
  const _Float16* Hrow = HinT + ((size_t)b * 16 + lm) * N_ + wave * 512 + lq * 8;
#pragma unroll 4
  for (int k = 0; k < 512; k += 32) {
    f16x8 a = *(const f16x8*)(Trow + k);
    f16x8 hb = *(const f16x8*)(Hrow + k);
    acc = __builtin_amdgcn_mfma_f32_16x16x32_f16(a, hb, acc, 0, 0, 0);
  }
#pragma unroll
  for (int r = 0; r < 4; ++r) red[wave][lq * 4 + r][lm] = acc[r];
  __syncthreads();
  int c = threadIdx.x >> 4, r = threadIdx.x & 15;
  float s = red[0][r][c] + red[1][r][c] + red[2][r][c] + red[3][r][c];
  size_t o = ((size_t)b * 16 + c) * N_ + m0 + r;
  if (HoutT) HoutT[o] = f2h(s);
  if (first) accT[o] = w * s; else accT[o] += w * s;
}

// hop3 fused with input projection: x0/xh = [ns, khop_acc] @ Win + b_in
__global__ __launch_bounds__(256) void khop3_input(const _Float16* __restrict__ Tb,
    const _Float16* __restrict__ HinT, const _Float16* __restrict__ nsT,
    const float* __restrict__ accT, const _Float16* __restrict__ Wint,
    const float* __restrict__ bin, float hw2,
    float* __restrict__ x0, _Float16* __restrict__ xh) {
  int b = blockIdx.y;
  int m0 = blockIdx.x * 16;
  int wave = threadIdx.x >> 6, lane = threadIdx.x & 63;
  int lm = lane & 15, lq = lane >> 4;
  __shared__ float red[4][16][17];
  __shared__ _Float16 in28s[16][32];
  f32x4 acc = {0.f, 0.f, 0.f, 0.f};
  const _Float16* Trow = Tb + ((size_t)b * N_ + m0 + lm) * N_ + wave * 512 + lq * 8;
  const _Float16* Hrow = HinT + ((size_t)b * 16 + lm) * N_ + wave * 512 + lq * 8;
#pragma unroll 4
  for (int k = 0; k < 512; k += 32) {
    f16x8 a = *(const f16x8*)(Trow + k);
    f16x8 hb = *(const f16x8*)(Hrow + k);
    acc = __builtin_amdgcn_mfma_f32_16x16x32_f16(a, hb, acc, 0, 0, 0);
  }
#pragma unroll
  for (int r = 0; r < 4; ++r) red[wave][lq * 4 + r][lm] = acc[r];
  __syncthreads();
  {
    int c = threadIdx.x >> 4, r = threadIdx.x & 15;
    float s = red[0][r][c] + red[1][r][c] + red[2][r][c] + red[3][r][c];
    if (c < 14) {
      float atot = accT[((size_t)b * 16 + c) * N_ + m0 + r] + hw2 * s;
      float nsv = (float)nsT[((size_t)b * 16 + c) * N_ + m0 + r];
      in28s[r][c] = f2h(nsv);
      in28s[r][14 + c] = f2h(atot);
    } else if (c == 14) {
      in28s[r][28] = (_Float16)0.f;
      in28s[r][29] = (_Float16)0.f;
    } else {
      in28s[r][30] = (_Float16)0.f;
      in28s[r][31] = (_Float16)0.f;
    }
  }
  __syncthreads();
  // input projection: 16 nodes x 256 cols = in28(16x32) @ Wint^T (K=32)
  f16x8 afrag = *(const f16x8*)(&in28s[lm][lq * 8]);
#pragma unroll
  for (int nt = 0; nt < 4; ++nt) {
    int n0 = wave * 64 + nt * 16;
    f16x8 bfrag = *(const f16x8*)(Wint + (size_t)(n0 + lm) * 32 + lq * 8);
    f32x4 c4 = {0.f, 0.f, 0.f, 0.f};
    c4 = __builtin_amdgcn_mfma_f32_16x16x32_f16(afrag, bfrag, c4, 0, 0, 0);
    float bv = bin[n0 + lm];
#pragma unroll
    for (int rg = 0; rg < 4; ++rg) {
      int rw = lq * 4 + rg;
      float val = c4[rg] + bv;
      size_t o = ((size_t)(b * N_ + m0 + rw)) * 256 + n0 + lm;
      x0[o] = val;
      xh[o] = f2h(val);
    }
  }
}

// C(M,N) = A(M,K,f16) @ Wt(N,K,f16)^T + bias; optional relu; fp32 and/or f16 out
__global__ __launch_bounds__(256) void gemm_kernel(const _Float16* __restrict__ A,
    const _Float16* __restrict__ Wt, const float* __restrict__ bias,
    float* __restrict__ Cf, _Float16* __restrict__ Ch,
    int N, int K, int relu) {
  int wave = threadIdx.x >> 6, lane = threadIdx.x & 63;
  int wy = wave >> 1, wx = wave & 1;
  int m0 = blockIdx.x * 64 + wy * 32;
  int n0 = blockIdx.y * 64 + wx * 32;
  int lm = lane & 15, lq = lane >> 4;
  f32x4 acc[2][2] = {};
  const _Float16* A0 = A + (size_t)(m0 + lm) * K + lq * 8;
  const _Float16* A1 = A0 + (size_t)16 * K;
  const _Float16* B0 = Wt + (size_t)(n0 + lm) * K + lq * 8;
  const _Float16* B1 = B0 + (size_t)16 * K;
  for (int k = 0; k < K; k += 32) {
    f16x8 a0 = *(const f16x8*)(A0 + k);
    f16x8 a1 = *(const f16x8*)(A1 + k);
    f16x8 b0 = *(const f16x8*)(B0 + k);
    f16x8 b1 = *(const f16x8*)(B1 + k);
    acc[0][0] = __builtin_amdgcn_mfma_f32_16x16x32_f16(a0, b0, acc[0][0], 0, 0, 0);
    acc[0][1] = __builtin_amdgcn_mfma_f32_16x16x32_f16(a0, b1, acc[0][1], 0, 0, 0);
    acc[1][0] = __builtin_amdgcn_mfma_f32_16x16x32_f16(a1, b0, acc[1][0], 0, 0, 0);
    acc[1][1] = __builtin_amdgcn_mfma_f32_16x16x32_f16(a1, b1, acc[1][1], 0, 0, 0);
  }
#pragma unroll
  for (int tm = 0; tm < 2; ++tm)
#pragma unroll
    for (int tn = 0; tn < 2; ++tn) {
      int col = n0 + tn * 16 + lm;
      float bvv = bias ? bias[col] : 0.f;
#pragma unroll
      for (int r = 0; r < 4; ++r) {
        int row = m0 + tm * 16 + lq * 4 + r;
        float val = acc[tm][tn][r] + bvv;
        if (relu) val = fmaxf(val, 0.f);
        size_t o = (size_t)row * N + col;
        if (Cf) Cf[o] = val;
        if (Ch) Ch[o] = f2h(val);
      }
    }
}

// one wave per node: online segment softmax over incoming edges (fp16 qkv)
__global__ __launch_bounds__(256) void attn_kernel(const _Float16* __restrict__ qkv,
    const int* __restrict__ offs, const int* __restrict__ perm,
    const int* __restrict__ srcf, const float* __restrict__ eb,
    _Float16* __restrict__ aggh) {
  int node = blockIdx.x * 4 + (threadIdx.x >> 6);
  int lane = threadIdx.x & 63;
  int h = lane >> 3;
  f16x4 qh = *(const f16x4*)(qkv + (size_t)node * 768 + lane * 4);
  float4 q4 = {(float)qh[0], (float)qh[1], (float)qh[2], (float)qh[3]};
  int beg = offs[node], end = offs[node + 1];
  float mx = -3.0e38f, den = 0.f;
  float4 acc = {0.f, 0.f, 0.f, 0.f};
  for (int j = beg; j < end; ++j) {
    int e = perm[j];
    int s = srcf[e];
    const _Float16* base = qkv + (size_t)s * 768 + lane * 4;
    f16x4 kh = *(const f16x4*)(base + 256);
    f16x4 vh = *(const f16x4*)(base + 512);
    float p = q4.x * (float)kh[0] + q4.y * (float)kh[1]
            + q4.z * (float)kh[2] + q4.w * (float)kh[3];
    p += __shfl_xor(p, 1);
    p += __shfl_xor(p, 2);
    p += __shfl_xor(p, 4);
    float score = p * 0.17677669529663687f + eb[(size_t)e * 8 + h];
    float nm = fmaxf(mx, score);
    float sc = __expf(mx - nm);
    float w = __expf(score - nm);
    den = den * sc + w;
    acc.x = acc.x * sc + w * (float)vh[0];
    acc.y = acc.y * sc + w * (float)vh[1];
    acc.z = acc.z * sc + w * (float)vh[2];
    acc.w = acc.w * sc + w * (float)vh[3];
    mx = nm;
  }
  float inv = den > 0.f ? 1.f / den : 0.f;
  f16x4 o;
  o[0] = f2h(acc.x * inv);
  o[1] = f2h(acc.y * inv);
  o[2] = f2h(acc.z * inv);
  o[3] = f2h(acc.w * inv);
  *(f16x4*)(aggh + (size_t)node * DM_ + lane * 4) = o;
}

// fused GEMM (M-tile 32, N=256 full) + residual + LayerNorm -> fp32 + fp16 out
__global__ __launch_bounds__(256) void gemm_res_ln(const _Float16* __restrict__ A,
    const _Float16* __restrict__ Wt, const float* __restrict__ bias,
    const float* __restrict__ res, const float* __restrict__ g,
    const float* __restrict__ bb, float* __restrict__ yF,
    _Float16* __restrict__ yH) {
  int m0 = blockIdx.x * 32;
  int wave = threadIdx.x >> 6, lane = threadIdx.x & 63;
  int lm = lane & 15, lq = lane >> 4;
  int n0 = wave * 64;
  f32x4 acc[2][4] = {};
  const _Float16* Ap = A + (size_t)(m0 + lm) * 256 + lq * 8;
  const _Float16* Bp = Wt + (size_t)(n0 + lm) * 256 + lq * 8;
  for (int k = 0; k < 256; k += 32) {
    f16x8 a0 = *(const f16x8*)(Ap + k);
    f16x8 a1 = *(const f16x8*)(Ap + 16 * 256 + k);
#pragma unroll
    for (int nt = 0; nt < 4; ++nt) {
      f16x8 bf = *(const f16x8*)(Bp + nt * 16 * 256 + k);
      acc[0][nt] = __builtin_amdgcn_mfma_f32_16x16x32_f16(a0, bf, acc[0][nt], 0, 0, 0);
      acc[1][nt] = __builtin_amdgcn_mfma_f32_16x16x32_f16(a1, bf, acc[1][nt], 0, 0, 0);
    }
  }
  float val[2][4][4];
  float rsum[2][4] = {}, rsq[2][4] = {};
#pragma unroll
  for (int mt = 0; mt < 2; ++mt)
#pragma unroll
    for (int nt = 0; nt < 4; ++nt) {
      int col = n0 + nt * 16 + lm;
      float bv = bias[col];
#pragma unroll
      for (int rg = 0; rg < 4; ++rg) {
        int row = m0 + mt * 16 + lq * 4 + rg;
        float x = acc[mt][nt][rg] + bv + res[(size_t)row * 256 + col];
        val[mt][nt][rg] = x;
        rsum[mt][rg] += x;
        rsq[mt][rg] += x * x;
      }
    }
#pragma unroll
  for (int mt = 0; mt < 2; ++mt)
#pragma unroll
    for (int rg = 0; rg < 4; ++rg)
      for (int off = 1; off < 16; off <<= 1) {
        rsum[mt][rg] += __shfl_xor(rsum[mt][rg], off);
        rsq[mt][rg] += __shfl_xor(rsq[mt][rg], off);
      }
  __shared__ float redS[32][4], redQ[32][4];
  if (lm == 0) {
#pragma unroll
    for (int mt = 0; mt < 2; ++mt)
#pragma unroll
      for (int rg = 0; rg < 4; ++rg) {
        int r = mt * 16 + lq * 4 + rg;
        redS[r][wave] = rsum[mt][rg];
        redQ[r][wave] = rsq[mt][rg];
      }
  }
  __syncthreads();
#pragma unroll
  for (int mt = 0; mt < 2; ++mt)
#pragma unroll
    for (int rg = 0; rg < 4; ++rg) {
      int r = mt * 16 + lq * 4 + rg;
      float tS = redS[r][0] + redS[r][1] + redS[r][2] + redS[r][3];
      float tQ = redQ[r][0] + redQ[r][1] + redQ[r][2] + redQ[r][3];
      float mu = tS * (1.f / 256.f);
      float var = tQ * (1.f / 256.f) - mu * mu;
      float rs = rsqrtf(var + 1e-5f);
      int row = m0 + r;
#pragma unroll
      for (int nt = 0; nt < 4; ++nt) {
        int col = n0 + nt * 16 + lm;
        float y = g[col] * (val[mt][nt][rg] - mu) * rs + bb[col];
        size_t o = (size_t)row * 256 + col;
        yF[o] = y;
        yH[o] = f2h(y);
      }
    }
}

// fused FFN2 GEMM (K=1024) + residual + LN2 + heads state update
__global__ __launch_bounds__(256) void ffn2_ln_heads(const _Float16* __restrict__ A,
    const _Float16* __restrict__ Wt, const float* __restrict__ bias,
    const float* __restrict__ res, const float* __restrict__ g,
    const float* __restrict__ bb, const float* __restrict__ Wh,
    const float* __restrict__ bh, const float* __restrict__ pm,
    const float* __restrict__ qm, float* __restrict__ v,
    float* __restrict__ th, float* __restrict__ m) {
  int m0 = blockIdx.x * 32;
  int wave = threadIdx.x >> 6, lane = threadIdx.x & 63;
  int lm = lane & 15, lq = lane >> 4;
  int n0 = wave * 64;
  f32x4 acc[2][4] = {};
  const _Float16* Ap = A + (size_t)(m0 + lm) * 1024 + lq * 8;
  const _Float16* Bp = Wt + (size_t)(n0 + lm) * 1024 + lq * 8;
  for (int k = 0; k < 1024; k += 32) {
    f16x8 a0 = *(const f16x8*)(Ap + k);
    f16x8 a1 = *(const f16x8*)(Ap + 16 * 1024 + k);
#pragma unroll
    for (int nt = 0; nt < 4; ++nt) {
      f16x8 bf = *(const f16x8*)(Bp + nt * 16 * 1024 + k);
      acc[0][nt] = __builtin_amdgcn_mfma_f32_16x16x32_f16(a0, bf, acc[0][nt], 0, 0, 0);
      acc[1][nt] = __builtin_amdgcn_mfma_f32_16x16x32_f16(a1, bf, acc[1][nt], 0, 0, 0);
    }
  }
  __shared__ float redS[32][4], redQ[32][4];
  __shared__ float xs[32][260];
  __shared__ float whs[3072];
  __shared__ float part[32][8][12];
  float val[2][4][4];
  float rsum[2][4] = {}, rsq[2][4] = {};
#pragma unroll
  for (int mt = 0; mt < 2; ++mt)
#pragma unroll
    for (int nt = 0; nt < 4; ++nt) {
      int col = n0 + nt * 16 + lm;
      float bv = bias[col];
#pragma unroll
      for (int rg = 0; rg < 4; ++rg) {
        int row = m0 + mt * 16 + lq * 4 + rg;
        float x = acc[mt][nt][rg] + bv + res[(size_t)row * 256 + col];
        val[mt][nt][rg] = x;
        rsum[mt][rg] += x;
        rsq[mt][rg] += x * x;
      }
    }
#pragma unroll
  for (int mt = 0; mt < 2; ++mt)
#pragma unroll
    for (int rg = 0; rg < 4; ++rg)
      for (int off = 1; off < 16; off <<= 1) {
        rsum[mt][rg] += __shfl_xor(rsum[mt][rg], off);
        rsq[mt][rg] += __shfl_xor(rsq[mt][rg], off);
      }
  if (lm == 0) {
#pragma unroll
    for (int mt = 0; mt < 2; ++mt)
#pragma unroll
      for (int rg = 0; rg < 4; ++rg) {
        int r = mt * 16 + lq * 4 + rg;
        redS[r][wave] = rsum[mt][rg];
        redQ[r][wave] = rsq[mt][rg];
      }
  }
  for (int i = threadIdx.x; i < 3072; i += 256) whs[i] = Wh[i];
  __syncthreads();
#pragma unroll
  for (int mt = 0; mt < 2; ++mt)
#pragma unroll
    for (int rg = 0; rg < 4; ++rg) {
      int r = mt * 16 + lq * 4 + rg;
      float tS = redS[r][0] + redS[r][1] + redS[r][2] + redS[r][3];
      float tQ = redQ[r][0] + redQ[r][1] + redQ[r][2] + redQ[r][3];
      float mu = tS * (1.f / 256.f);
      float var = tQ * (1.f / 256.f) - mu * mu;
      float rs = rsqrtf(var + 1e-5f);
#pragma unroll
      for (int nt = 0; nt < 4; ++nt) {
        int col = n0 + nt * 16 + lm;
        xs[r][col] = g[col] * (val[mt][nt][rg] - mu) * rs + bb[col];
      }
    }
  __syncthreads();
  // heads: 12 dots per row over 256 cols
  {
    int rw = threadIdx.x & 31, grp = threadIdx.x >> 5;
    float p[12] = {};
    for (int c = 0; c < 32; ++c) {
      int col = grp * 32 + c;
      float xv = xs[rw][col];
#pragma unroll
      for (int o = 0; o < 12; ++o) p[o] += xv * whs[col * 12 + o];
    }
#pragma unroll
    for (int o = 0; o < 12; ++o) part[rw][grp][o] = p[o];
  }
  __syncthreads();
  if (threadIdx.x < 32) {
    int node = m0 + threadIdx.x;
    float tot[12];
#pragma unroll
    for (int o = 0; o < 12; ++o) {
      float s = bh[o];
#pragma unroll
      for (int grp = 0; grp < 8; ++grp) s += part[threadIdx.x][grp][o];
      tot[o] = s;
    }
    th[node] += tot[0] * pm[node];
    v[node] += tot[1] * qm[node];
#pragma unroll
    for (int d = 0; d < 10; ++d) m[(size_t)node * 10 + d] = tot[2 + d];
  }
}

__global__ void out_kernel(const float* __restrict__ v, const float* __restrict__ th,
                           float* __restrict__ out) {
  int t = blockIdx.x * blockDim.x + threadIdx.x;
  if (t >= BN_) return;
  out[2 * t] = v[t];
  out[2 * t + 1] = th[t];
}

// ---------------- launcher ----------------

extern "C" void kernel_launch(void* const* d_in, const int* in_sizes, int n_in,
                              void* d_out, int out_size, void* d_ws, size_t ws_size,
                              hipStream_t stream) {
  const int* bus = (const int*)d_in[0];
  const int* ei = (const int*)d_in[1];
  const float* G = (const float*)d_in[2];
  const float* Bm = (const float*)d_in[3];
  const float* P = (const float*)d_in[4];
  const float* Q = (const float*)d_in[5];
  const float* V0 = (const float*)d_in[6];
  const float* efeat = (const float*)d_in[7];
  const float* Win = (const float*)d_in[8];
  const float* bin = (const float*)d_in[9];
  const float* Wq = (const float*)d_in[10];
  const float* bq = (const float*)d_in[11];
  const float* Wk = (const float*)d_in[12];
  const float* bk = (const float*)d_in[13];
  const float* Wv = (const float*)d_in[14];
  const float* bv = (const float*)d_in[15];
  const float* Wo = (const float*)d_in[16];
  const float* bo = (const float*)d_in[17];
  const float* We = (const float*)d_in[18];
  const float* be = (const float*)d_in[19];
  const float* g1 = (const float*)d_in[20];
  const float* b1 = (const float*)d_in[21];
  const float* g2 = (const float*)d_in[22];
  const float* b2 = (const float*)d_in[23];
  const float* Wf1 = (const float*)d_in[24];
  const float* bf1 = (const float*)d_in[25];
  const float* Wf2 = (const float*)d_in[26];
  const float* bf2 = (const float*)d_in[27];
  const float* Wth = (const float*)d_in[28];
  const float* bth = (const float*)d_in[29];
  const float* Wvh = (const float*)d_in[30];
  const float* bvh = (const float*)d_in[31];
  const float* Wm = (const float*)d_in[32];
  const float* bm = (const float*)d_in[33];
  float* out = (float*)d_out;

  char* p = (char*)d_ws;
  auto alloc = [&](size_t bytes) -> void* {
    void* r = (void*)p;
    p += (bytes + 255) & ~(size_t)255;
    return r;
  };
  _Float16* Tb = (_Float16*)alloc((size_t)BN_ * N_ * 2);
  _Float16* nsT = (_Float16*)alloc((size_t)B_ * 16 * N_ * 2);
  _Float16* HTa = (_Float16*)alloc((size_t)B_ * 16 * N_ * 2);
  _Float16* HTb = (_Float16*)alloc((size_t)B_ * 16 * N_ * 2);
  float* accT = (float*)alloc((size_t)B_ * 16 * N_ * 4);
  _Float16* qkvh = (_Float16*)alloc((size_t)BN_ * 768 * 2);
  float* x0 = (float*)alloc((size_t)BN_ * 256 * 4);
  float* x1 = (float*)alloc((size_t)BN_ * 256 * 4);
  _Float16* xhA = (_Float16*)alloc((size_t)BN_ * 256 * 2);
  _Float16* xhB = (_Float16*)alloc((size_t)BN_ * 256 * 2);
  _Float16* hbuf = (_Float16*)alloc((size_t)BN_ * 1024 * 2);
  float* eb = (float*)alloc((size_t)BE_ * 8 * 4);
  int* srcf = (int*)alloc((size_t)BE_ * 4);
  int* dstf = (int*)alloc((size_t)BE_ * 4);
  int* counts = (int*)alloc((size_t)BN_ * 4);
  int* offs = (int*)alloc((size_t)(BN_ + 1) * 4);
  int* cursor = (int*)alloc((size_t)BN_ * 4);
  int* perm = (int*)alloc((size_t)BE_ * 4);
  _Float16* Wqkvt = (_Float16*)alloc(768 * 256 * 2);
  _Float16* Wot = (_Float16*)alloc(256 * 256 * 2);
  _Float16* Wf1t = (_Float16*)alloc(1024 * 256 * 2);
  _Float16* Wf2t = (_Float16*)alloc(256 * 1024 * 2);
  _Float16* Wint = (_Float16*)alloc(256 * 32 * 2);
  float* Wheads = (float*)alloc(30 * 3072 * 4);
  float* bheads = (float*)alloc(30 * 12 * 4);
  float* bqkv = (float*)alloc(768 * 4);
  float* v = (float*)alloc((size_t)BN_ * 4);
  float* th = (float*)alloc((size_t)BN_ * 4);
  float* pm = (float*)alloc((size_t)BN_ * 4);
  float* qm = (float*)alloc((size_t)BN_ * 4);
  float* m = (float*)alloc((size_t)BN_ * 10 * 4);

  // optional fp16 G/Bm (placed last; used only if workspace is big enough)
  size_t gb_bytes = (size_t)B_ * N_ * N_ * 2;
  size_t used = (size_t)(p - (char*)d_ws);
  bool f16gb = (used + 2 * (gb_bytes + 256) <= ws_size);
  _Float16* Gh = nullptr;
  _Float16* Bh = nullptr;
  if (f16gb) {
    Gh = (_Float16*)alloc(gb_bytes);
    Bh = (_Float16*)alloc(gb_bytes);
  }

  double hwd[3], z = 0.0;
  for (int i = 0; i < 3; ++i) {
    hwd[i] = exp(-((double)(i + 1) * (i + 1)) / (2.0 * 1.5 * 1.5));
    z += hwd[i];
  }
  float hw0 = (float)(hwd[0] / z), hw1 = (float)(hwd[1] / z), hw2 = (float)(hwd[2] / z);

  init_state<<<32, 256, 0, stream>>>(bus, V0, v, th, m, pm, qm, counts);
  build_T<<<8192, 256, 0, stream>>>(G, Bm, Tb);
  if (f16gb) cast_GB<<<16384, 256, 0, stream>>>(G, Bm, Gh, Bh);
  edge_prep<<<BE_ / 256, 256, 0, stream>>>(ei, efeat, We, be, eb, srcf, dstf, counts);
  scan_kernel<<<1, 256, 0, stream>>>(counts, offs, cursor);
  scatter_kernel<<<BE_ / 256, 256, 0, stream>>>(dstf, cursor, perm);
  prep_weights<<<(887912 + 255) / 256, 256, 0, stream>>>(
      Wq, bq, Wk, bk, Wv, bv, Wo, Wf1, Wf2, Wth, bth, Wvh, bvh, Wm, bm, Win,
      Wqkvt, bqkv, Wot, Wf1t, Wf2t, Wheads, bheads, Wint);

  for (int k = 0; k < 30; ++k) {
    if (f16gb)
      matvec_ns_f16<<<dim3(128, 4), 256, 0, stream>>>(Gh, Bh, v, th, P, Q, pm, qm,
                                                      m, nsT);
    else
      matvec_ns_f32<<<dim3(128, 4), 256, 0, stream>>>(G, Bm, v, th, P, Q, pm, qm,
                                                      m, nsT);
    khop_kernel<<<dim3(128, 4), 256, 0, stream>>>(Tb, nsT, HTa, accT, hw0, 1);
    khop_kernel<<<dim3(128, 4), 256, 0, stream>>>(Tb, HTa, HTb, accT, hw1, 0);
    khop3_input<<<dim3(128, 4), 256, 0, stream>>>(Tb, HTb, nsT, accT, Wint, bin,
                                                  hw2, x0, xhA);
    gemm_kernel<<<dim3(128, 12), 256, 0, stream>>>(xhA, Wqkvt, bqkv, nullptr, qkvh,
                                                   768, 256, 0);
    attn_kernel<<<2048, 256, 0, stream>>>(qkvh, offs, perm, srcf, eb, xhB);
    gemm_res_ln<<<256, 256, 0, stream>>>(xhB, Wot, bo, x0, g1, b1, x1, xhA);
    gemm_kernel<<<dim3(128, 16), 256, 0, stream>>>(xhA, Wf1t, bf1, nullptr, hbuf,
                                                   1024, 256, 1);
    ffn2_ln_heads<<<256, 256, 0, stream>>>(hbuf, Wf2t, bf2, x1, g2, b2,
                                           Wheads + k * 3072, bheads + k * 12,
                                           pm, qm, v, th, m);
  }
  out_kernel<<<32, 256, 0, stream>>>(v, th, out);
}